// Round 6
// baseline (1292.391 us; speedup 1.0000x reference)
//
#include <hip/hip_runtime.h>

#define NLEVELS 16
#define TSIZE 131072
#define TMASK (TSIZE - 1)
#define NBUCK 32768           // 8 trees x 4096 morton cells (4 bits/dim)

typedef float f32x4 __attribute__((ext_vector_type(4)));

__device__ __constant__ float RM1_TAB[16] = {
    15.f, 21.f, 29.f, 40.f, 54.f, 74.f, 101.f, 138.f,
    187.f, 255.f, 347.f, 471.f, 641.f, 871.f, 1183.f, 1607.f
};

// spread 4 bits to stride-3 positions 0,3,6,9
__device__ __forceinline__ unsigned spread4(unsigned v) {
    v = (v | (v << 4)) & 0x0C3u;
    v = (v | (v << 2)) & 0x249u;
    return v;
}

__device__ __forceinline__ unsigned bucket_key(float x, float y, float z, unsigned tree) {
    const int cx = min(max((int)((x * 0.5f + 0.5f) * 16.f), 0), 15);
    const int cy = min(max((int)((y * 0.5f + 0.5f) * 16.f), 0), 15);
    const int cz = min(max((int)((z * 0.5f + 0.5f) * 16.f), 0), 15);
    const unsigned m = spread4((unsigned)cx) | (spread4((unsigned)cy) << 1)
                     | (spread4((unsigned)cz) << 2);
    return (tree << 12) | m;
}

// ---------------- counting sort by (tree, morton12) ----------------

__global__ __launch_bounds__(256) void k_hist(const float* __restrict__ xs,
                                              const int* __restrict__ inds, int N,
                                              unsigned* __restrict__ hist) {
    const int i = blockIdx.x * 256 + threadIdx.x;
    if (i >= N) return;
    const unsigned key = bucket_key(xs[3 * i], xs[3 * i + 1], xs[3 * i + 2],
                                    (unsigned)(inds[i] & 7));
    atomicAdd(&hist[key], 1u);
}

__global__ __launch_bounds__(1024) void k_scan(const unsigned* __restrict__ hist,
                                               unsigned* __restrict__ cursor) {
    __shared__ unsigned sums[1024];
    const int t = threadIdx.x;
    const int per = NBUCK / 1024;          // 32
    unsigned s = 0;
    #pragma unroll
    for (int j = 0; j < per; ++j) s += hist[t * per + j];
    sums[t] = s;
    __syncthreads();
    for (int off = 1; off < 1024; off <<= 1) {
        const unsigned add = (t >= off) ? sums[t - off] : 0u;
        __syncthreads();
        sums[t] += add;
        __syncthreads();
    }
    unsigned run = (t == 0) ? 0u : sums[t - 1];
    #pragma unroll
    for (int j = 0; j < per; ++j) {
        cursor[t * per + j] = run;
        run += hist[t * per + j];
    }
}

__global__ __launch_bounds__(256) void k_scatter(const float* __restrict__ xs,
                                                 const int* __restrict__ inds, int N,
                                                 unsigned* __restrict__ cursor,
                                                 float4* __restrict__ sorted) {
    const int i = blockIdx.x * 256 + threadIdx.x;
    if (i >= N) return;
    const float x = xs[3 * i], y = xs[3 * i + 1], z = xs[3 * i + 2];
    const unsigned tree = (unsigned)(inds[i] & 7);
    const unsigned key = bucket_key(x, y, z, tree);
    const unsigned pos = atomicAdd(&cursor[key], 1u);
    sorted[pos] = make_float4(x, y, z, __uint_as_float(((unsigned)i) | (tree << 24)));
}

// ---------------- task body: chunk t, level pair (v, 15-v) ----------------

__device__ __forceinline__ void do_task(const float4* __restrict__ sorted,
                                        const float* __restrict__ params,
                                        float4* __restrict__ ws2,
                                        float4* __restrict__ out4,
                                        int N, int nc, int direct,
                                        int v, int t) {
    const int i = t * 256 + (int)threadIdx.x;
    if (i >= N) return;

    const float4 p = sorted[i];
    const unsigned wbits = __float_as_uint(p.w);
    const int n = (int)(wbits & 0xFFFFFFu);
    const int tree = (int)(wbits >> 24);

    const int levels[2] = { v, 15 - v };
    float acc[4];

    #pragma unroll
    for (int kk = 0; kk < 2; ++kk) {
        const int l = levels[kk];
        const float rm1 = RM1_TAB[l];
        const int rmax = (int)rm1;

        const float px = (p.x * 0.5f + 0.5f) * rm1;
        const float py = (p.y * 0.5f + 0.5f) * rm1;
        const float pz = (p.z * 0.5f + 0.5f) * rm1;
        const float fx = floorf(px), fy = floorf(py), fz = floorf(pz);
        const float wx = px - fx, wy = py - fy, wz = pz - fz;
        const int ix = (int)fx, iy = (int)fy, iz = (int)fz;

        const int x0 = min(max(ix, 0), rmax), x1 = min(max(ix + 1, 0), rmax);
        const int y0 = min(max(iy, 0), rmax), y1 = min(max(iy + 1, 0), rmax);
        const int z0 = min(max(iz, 0), rmax), z1 = min(max(iz + 1, 0), rmax);

        const unsigned hx0 = (unsigned)x0;
        const unsigned hx1 = (unsigned)x1;
        const unsigned hy0 = (unsigned)y0 * 2654435761u;
        const unsigned hy1 = (unsigned)y1 * 2654435761u;
        const unsigned hz0 = (unsigned)z0 * 805459861u;
        const unsigned hz1 = (unsigned)z1 * 805459861u;

        const float2* __restrict__ tbl =
            (const float2*)(params + (size_t)(tree * NLEVELS + l) * (TSIZE * 2));

        const unsigned m00 = hy0 ^ hz0;
        const unsigned m01 = hy0 ^ hz1;
        const unsigned m10 = hy1 ^ hz0;
        const unsigned m11 = hy1 ^ hz1;
        const unsigned i000 = (hx0 ^ m00) & TMASK;
        const unsigned i001 = (hx0 ^ m01) & TMASK;
        const unsigned i010 = (hx0 ^ m10) & TMASK;
        const unsigned i011 = (hx0 ^ m11) & TMASK;

        float2 f000, f001, f010, f011, f100, f101, f110, f111;

        // x-prime is 1: if x0 even and x1==x0+1, the two x-corners are
        // ADJACENT table entries {2j,2j+1} -> one aligned float4 covers both.
        const bool pairOK = ((x0 & 1) == 0) && (x1 == x0 + 1);
        if (pairOK) {
            const float4* __restrict__ tbl4 = (const float4*)tbl;
            const float4 q00 = tbl4[i000 >> 1];
            const float4 q01 = tbl4[i001 >> 1];
            const float4 q10 = tbl4[i010 >> 1];
            const float4 q11 = tbl4[i011 >> 1];
            f000 = (i000 & 1) ? make_float2(q00.z, q00.w) : make_float2(q00.x, q00.y);
            f100 = (i000 & 1) ? make_float2(q00.x, q00.y) : make_float2(q00.z, q00.w);
            f001 = (i001 & 1) ? make_float2(q01.z, q01.w) : make_float2(q01.x, q01.y);
            f101 = (i001 & 1) ? make_float2(q01.x, q01.y) : make_float2(q01.z, q01.w);
            f010 = (i010 & 1) ? make_float2(q10.z, q10.w) : make_float2(q10.x, q10.y);
            f110 = (i010 & 1) ? make_float2(q10.x, q10.y) : make_float2(q10.z, q10.w);
            f011 = (i011 & 1) ? make_float2(q11.z, q11.w) : make_float2(q11.x, q11.y);
            f111 = (i011 & 1) ? make_float2(q11.x, q11.y) : make_float2(q11.z, q11.w);
        } else {
            const unsigned i100 = (hx1 ^ m00) & TMASK;
            const unsigned i101 = (hx1 ^ m01) & TMASK;
            const unsigned i110 = (hx1 ^ m10) & TMASK;
            const unsigned i111 = (hx1 ^ m11) & TMASK;
            f000 = tbl[i000]; f001 = tbl[i001];
            f010 = tbl[i010]; f011 = tbl[i011];
            f100 = tbl[i100]; f101 = tbl[i101];
            f110 = tbl[i110]; f111 = tbl[i111];
        }

        const float wx0 = 1.f - wx, wy0 = 1.f - wy, wz0 = 1.f - wz;

        const float w000 = wx0 * wy0 * wz0;
        const float w001 = wx0 * wy0 * wz;
        const float w010 = wx0 * wy  * wz0;
        const float w011 = wx0 * wy  * wz;
        const float w100 = wx  * wy0 * wz0;
        const float w101 = wx  * wy0 * wz;
        const float w110 = wx  * wy  * wz0;
        const float w111 = wx  * wy  * wz;

        float a0 = 0.f, a1 = 0.f;
        a0 = fmaf(w000, f000.x, a0); a1 = fmaf(w000, f000.y, a1);
        a0 = fmaf(w001, f001.x, a0); a1 = fmaf(w001, f001.y, a1);
        a0 = fmaf(w010, f010.x, a0); a1 = fmaf(w010, f010.y, a1);
        a0 = fmaf(w011, f011.x, a0); a1 = fmaf(w011, f011.y, a1);
        a0 = fmaf(w100, f100.x, a0); a1 = fmaf(w100, f100.y, a1);
        a0 = fmaf(w101, f101.x, a0); a1 = fmaf(w101, f101.y, a1);
        a0 = fmaf(w110, f110.x, a0); a1 = fmaf(w110, f110.y, a1);
        a0 = fmaf(w111, f111.x, a0); a1 = fmaf(w111, f111.y, a1);

        acc[2 * kk + 0] = a0;
        acc[2 * kk + 1] = a1;
    }

    if (direct) {
        ((float2*)out4)[(size_t)n * 16 + levels[0]] = make_float2(acc[0], acc[1]);
        ((float2*)out4)[(size_t)n * 16 + levels[1]] = make_float2(acc[2], acc[3]);
    } else {
        const float4 o = make_float4(acc[0], acc[1], acc[2], acc[3]);
        const size_t stride = (size_t)nc * 256;
        __builtin_nontemporal_store(*(const f32x4*)&o,
                                    (f32x4*)&ws2[(size_t)v * stride + i]);
    }
}

// ---------------- main gather kernel: persistent blocks + work stealing ----
// Home queue j = blockIdx.x & 7 (XCD round-robin). Queue v's tasks = chunks
// of level pair (v, 15-v) -> per-XCD table working set stays 2 MB per tree.
// When home queue drains, steal from (j+1)&7, ... -> self-balancing load.

__global__ __launch_bounds__(256) void k_main(const float4* __restrict__ sorted,
                                              const float* __restrict__ params,
                                              float4* __restrict__ ws2,
                                              float4* __restrict__ out4,
                                              unsigned* __restrict__ q,
                                              int N, int nc, int direct) {
    __shared__ unsigned s_t;
    const int j = blockIdx.x & 7;

    for (int v0 = 0; v0 < 8; ++v0) {
        const int v = (j + v0) & 7;
        for (;;) {
            if (threadIdx.x == 0) s_t = atomicAdd(&q[v], 1u);
            __syncthreads();
            const unsigned t = s_t;
            __syncthreads();
            if (t >= (unsigned)nc) break;
            do_task(sorted, params, ws2, out4, N, nc, direct, v, (int)t);
        }
    }
}

// ---------------- un-permute: sorted rows -> out rows ----------------
// stream v carries levels (v, 15-v); reassemble the 32-float row in registers.

__global__ __launch_bounds__(256) void k_final(const float4* __restrict__ sorted,
                                               const float4* __restrict__ ws2,
                                               float4* __restrict__ out4,
                                               int N, int nc) {
    const int i = blockIdx.x * 256 + threadIdx.x;
    if (i >= N) return;
    const unsigned wbits = __float_as_uint(sorted[i].w);
    const int n = (int)(wbits & 0xFFFFFFu);
    const size_t stride = (size_t)nc * 256;

    float4 q[8];
    #pragma unroll
    for (int j = 0; j < 8; ++j) {
        f32x4 v = __builtin_nontemporal_load((const f32x4*)&ws2[(size_t)j * stride + i]);
        q[j] = *(const float4*)&v;
    }
    // float2 slot l: l<8 -> (q[l].x, q[l].y); l>=8 -> (q[15-l].z, q[15-l].w)
    #pragma unroll
    for (int kk = 0; kk < 8; ++kk) {
        float4 o;
        if (kk < 4) {
            o = make_float4(q[2 * kk].x, q[2 * kk].y, q[2 * kk + 1].x, q[2 * kk + 1].y);
        } else {
            o = make_float4(q[15 - 2 * kk].z, q[15 - 2 * kk].w,
                            q[14 - 2 * kk].z, q[14 - 2 * kk].w);
        }
        out4[(size_t)n * 8 + kk] = o;
    }
}

// ---------------- fallback (fused one-pass) ----------------

__global__ __launch_bounds__(256) void lotd_fwd_fused(
    const float* __restrict__ xs, const float* __restrict__ params,
    const int* __restrict__ inds, float* __restrict__ out, int N)
{
    const int g = blockIdx.x * 256 + threadIdx.x;
    const int n = g >> 4;
    if (n >= N) return;
    const int l = g & 15;
    const float rm1 = RM1_TAB[l];
    const int rmax = (int)rm1;
    const float x = xs[3 * n], y = xs[3 * n + 1], z = xs[3 * n + 2];
    const int tree = inds[n];
    const float px = (x * 0.5f + 0.5f) * rm1;
    const float py = (y * 0.5f + 0.5f) * rm1;
    const float pz = (z * 0.5f + 0.5f) * rm1;
    const float fx = floorf(px), fy = floorf(py), fz = floorf(pz);
    const float wx = px - fx, wy = py - fy, wz = pz - fz;
    const int ix = (int)fx, iy = (int)fy, iz = (int)fz;
    const int x0 = min(max(ix, 0), rmax), x1 = min(max(ix + 1, 0), rmax);
    const int y0 = min(max(iy, 0), rmax), y1 = min(max(iy + 1, 0), rmax);
    const int z0 = min(max(iz, 0), rmax), z1 = min(max(iz + 1, 0), rmax);
    const unsigned hx0 = (unsigned)x0, hx1 = (unsigned)x1;
    const unsigned hy0 = (unsigned)y0 * 2654435761u, hy1 = (unsigned)y1 * 2654435761u;
    const unsigned hz0 = (unsigned)z0 * 805459861u,  hz1 = (unsigned)z1 * 805459861u;
    const float2* tbl = (const float2*)(params + (size_t)(tree * NLEVELS + l) * (TSIZE * 2));
    const float2 f000 = tbl[(hx0 ^ hy0 ^ hz0) & TMASK];
    const float2 f001 = tbl[(hx0 ^ hy0 ^ hz1) & TMASK];
    const float2 f010 = tbl[(hx0 ^ hy1 ^ hz0) & TMASK];
    const float2 f011 = tbl[(hx0 ^ hy1 ^ hz1) & TMASK];
    const float2 f100 = tbl[(hx1 ^ hy0 ^ hz0) & TMASK];
    const float2 f101 = tbl[(hx1 ^ hy0 ^ hz1) & TMASK];
    const float2 f110 = tbl[(hx1 ^ hy1 ^ hz0) & TMASK];
    const float2 f111 = tbl[(hx1 ^ hy1 ^ hz1) & TMASK];
    const float wx0 = 1.f - wx, wy0 = 1.f - wy, wz0 = 1.f - wz;
    float a0 = 0.f, a1 = 0.f;
    a0 = fmaf(wx0*wy0*wz0, f000.x, a0); a1 = fmaf(wx0*wy0*wz0, f000.y, a1);
    a0 = fmaf(wx0*wy0*wz , f001.x, a0); a1 = fmaf(wx0*wy0*wz , f001.y, a1);
    a0 = fmaf(wx0*wy *wz0, f010.x, a0); a1 = fmaf(wx0*wy *wz0, f010.y, a1);
    a0 = fmaf(wx0*wy *wz , f011.x, a0); a1 = fmaf(wx0*wy *wz , f011.y, a1);
    a0 = fmaf(wx *wy0*wz0, f100.x, a0); a1 = fmaf(wx *wy0*wz0, f100.y, a1);
    a0 = fmaf(wx *wy0*wz , f101.x, a0); a1 = fmaf(wx *wy0*wz , f101.y, a1);
    a0 = fmaf(wx *wy *wz0, f110.x, a0); a1 = fmaf(wx *wy *wz0, f110.y, a1);
    a0 = fmaf(wx *wy *wz , f111.x, a0); a1 = fmaf(wx *wy *wz , f111.y, a1);
    ((float2*)out)[(size_t)n * 16 + l] = make_float2(a0, a1);
}

extern "C" void kernel_launch(void* const* d_in, const int* in_sizes, int n_in,
                              void* d_out, int out_size, void* d_ws, size_t ws_size,
                              hipStream_t stream) {
    const float* xs     = (const float*)d_in[0];
    const float* params = (const float*)d_in[1];
    const int*   inds   = (const int*)d_in[2];
    float*       out    = (float*)d_out;

    const int N = in_sizes[0] / 3;
    const int nc = (N + 255) / 256;

    const size_t hist_bytes   = (size_t)NBUCK * 4;               // 128 KB
    const size_t q_bytes      = 256;                             // 8 queue counters, padded
    const size_t head_bytes   = hist_bytes + q_bytes + hist_bytes; // hist, q, cursor
    const size_t sorted_bytes = ((size_t)N * 16 + 255) & ~(size_t)255;
    const size_t ws2_bytes    = (size_t)nc * 256 * 8 * 16;
    const size_t need_B = head_bytes + sorted_bytes;
    const size_t need_A = need_B + ws2_bytes;

    if (ws_size < need_B) {
        const int total = N * NLEVELS;
        lotd_fwd_fused<<<(total + 255) / 256, 256, 0, stream>>>(xs, params, inds, out, N);
        return;
    }

    unsigned* hist   = (unsigned*)d_ws;
    unsigned* q      = (unsigned*)((char*)d_ws + hist_bytes);
    unsigned* cursor = (unsigned*)((char*)d_ws + hist_bytes + q_bytes);
    float4*   sorted = (float4*)((char*)d_ws + head_bytes);
    float4*   ws2    = (float4*)((char*)d_ws + head_bytes + sorted_bytes);

    hipMemsetAsync(hist, 0, hist_bytes + q_bytes, stream);   // zero hist + queues
    k_hist<<<nc, 256, 0, stream>>>(xs, inds, N, hist);
    k_scan<<<1, 1024, 0, stream>>>(hist, cursor);
    k_scatter<<<nc, 256, 0, stream>>>(xs, inds, N, cursor, sorted);

    const int direct = (ws_size < need_A) ? 1 : 0;
    // persistent: 8 XCDs x 256 blocks (<= resident capacity at 4 waves/block)
    k_main<<<2048, 256, 0, stream>>>(sorted, params,
                                     direct ? nullptr : ws2,
                                     (float4*)out, q, N, nc, direct);
    if (!direct)
        k_final<<<nc, 256, 0, stream>>>(sorted, ws2, (float4*)out, N, nc);
}

// Round 7
// 763.427 us; speedup vs baseline: 1.6929x; 1.6929x over previous
//
#include <hip/hip_runtime.h>

#define NLEVELS 16
#define TSIZE 131072
#define TMASK (TSIZE - 1)
#define NBUCK 32768           // 8 trees x 4096 morton cells (4 bits/dim)

typedef float f32x4 __attribute__((ext_vector_type(4)));

__device__ __constant__ float RM1_TAB[16] = {
    15.f, 21.f, 29.f, 40.f, 54.f, 74.f, 101.f, 138.f,
    187.f, 255.f, 347.f, 471.f, 641.f, 871.f, 1183.f, 1607.f
};

// spread 4 bits to stride-3 positions 0,3,6,9
__device__ __forceinline__ unsigned spread4(unsigned v) {
    v = (v | (v << 4)) & 0x0C3u;
    v = (v | (v << 2)) & 0x249u;
    return v;
}

__device__ __forceinline__ unsigned bucket_key(float x, float y, float z, unsigned tree) {
    const int cx = min(max((int)((x * 0.5f + 0.5f) * 16.f), 0), 15);
    const int cy = min(max((int)((y * 0.5f + 0.5f) * 16.f), 0), 15);
    const int cz = min(max((int)((z * 0.5f + 0.5f) * 16.f), 0), 15);
    const unsigned m = spread4((unsigned)cx) | (spread4((unsigned)cy) << 1)
                     | (spread4((unsigned)cz) << 2);
    return (tree << 12) | m;
}

// ---------------- counting sort by (tree, morton12) ----------------

__global__ __launch_bounds__(256) void k_hist(const float* __restrict__ xs,
                                              const int* __restrict__ inds, int N,
                                              unsigned* __restrict__ hist) {
    const int i = blockIdx.x * 256 + threadIdx.x;
    if (i >= N) return;
    const unsigned key = bucket_key(xs[3 * i], xs[3 * i + 1], xs[3 * i + 2],
                                    (unsigned)(inds[i] & 7));
    atomicAdd(&hist[key], 1u);
}

__global__ __launch_bounds__(1024) void k_scan(const unsigned* __restrict__ hist,
                                               unsigned* __restrict__ cursor) {
    __shared__ unsigned sums[1024];
    const int t = threadIdx.x;
    const int per = NBUCK / 1024;          // 32
    unsigned s = 0;
    #pragma unroll
    for (int j = 0; j < per; ++j) s += hist[t * per + j];
    sums[t] = s;
    __syncthreads();
    for (int off = 1; off < 1024; off <<= 1) {
        const unsigned add = (t >= off) ? sums[t - off] : 0u;
        __syncthreads();
        sums[t] += add;
        __syncthreads();
    }
    unsigned run = (t == 0) ? 0u : sums[t - 1];
    #pragma unroll
    for (int j = 0; j < per; ++j) {
        cursor[t * per + j] = run;
        run += hist[t * per + j];
    }
}

__global__ __launch_bounds__(256) void k_scatter(const float* __restrict__ xs,
                                                 const int* __restrict__ inds, int N,
                                                 unsigned* __restrict__ cursor,
                                                 float4* __restrict__ sorted) {
    const int i = blockIdx.x * 256 + threadIdx.x;
    if (i >= N) return;
    const float x = xs[3 * i], y = xs[3 * i + 1], z = xs[3 * i + 2];
    const unsigned tree = (unsigned)(inds[i] & 7);
    const unsigned key = bucket_key(x, y, z, tree);
    const unsigned pos = atomicAdd(&cursor[key], 1u);
    sorted[pos] = make_float4(x, y, z, __uint_as_float(((unsigned)i) | (tree << 24)));
}

// ---------------- main gather kernel ----------------
// Static, exactly-balanced mapping: j = b&7 (XCD via round-robin dispatch),
// chunk = b>>3 walks morton-sorted points, band = chunk/band_sz (8 bands,
// band ~= one tree), level pair v = (j+band)&7. Every XCD executes every
// level pair on exactly 1/8 of the chunks -> equal per-XCD totals, while the
// instantaneous window keeps one pair + one tree (2 MB, L2-resident) per XCD.

__global__ __launch_bounds__(256) void k_main(const float4* __restrict__ sorted,
                                              const float* __restrict__ params,
                                              float4* __restrict__ ws2,   // [8][nc*256]
                                              float4* __restrict__ out4,  // direct mode
                                              int N, int nc, int band_sz, int direct) {
    const int b = blockIdx.x;
    const int j = b & 7;
    const int chunk = b >> 3;
    const int band = chunk / band_sz;
    const int v = (j + band) & 7;
    const int i = chunk * 256 + threadIdx.x;
    if (i >= N) return;

    const float4 p = sorted[i];
    const unsigned wbits = __float_as_uint(p.w);
    const int n = (int)(wbits & 0xFFFFFFu);
    const int tree = (int)(wbits >> 24);

    const int levels[2] = { v, 15 - v };
    float acc[4];

    #pragma unroll
    for (int kk = 0; kk < 2; ++kk) {
        const int l = levels[kk];
        const float rm1 = RM1_TAB[l];
        const int rmax = (int)rm1;

        const float px = (p.x * 0.5f + 0.5f) * rm1;
        const float py = (p.y * 0.5f + 0.5f) * rm1;
        const float pz = (p.z * 0.5f + 0.5f) * rm1;
        const float fx = floorf(px), fy = floorf(py), fz = floorf(pz);
        const float wx = px - fx, wy = py - fy, wz = pz - fz;
        const int ix = (int)fx, iy = (int)fy, iz = (int)fz;

        const int x0 = min(max(ix, 0), rmax), x1 = min(max(ix + 1, 0), rmax);
        const int y0 = min(max(iy, 0), rmax), y1 = min(max(iy + 1, 0), rmax);
        const int z0 = min(max(iz, 0), rmax), z1 = min(max(iz + 1, 0), rmax);

        const unsigned hx0 = (unsigned)x0;
        const unsigned hx1 = (unsigned)x1;
        const unsigned hy0 = (unsigned)y0 * 2654435761u;
        const unsigned hy1 = (unsigned)y1 * 2654435761u;
        const unsigned hz0 = (unsigned)z0 * 805459861u;
        const unsigned hz1 = (unsigned)z1 * 805459861u;

        const float2* __restrict__ tbl =
            (const float2*)(params + (size_t)(tree * NLEVELS + l) * (TSIZE * 2));

        const unsigned m00 = hy0 ^ hz0;
        const unsigned m01 = hy0 ^ hz1;
        const unsigned m10 = hy1 ^ hz0;
        const unsigned m11 = hy1 ^ hz1;
        const unsigned i000 = (hx0 ^ m00) & TMASK;
        const unsigned i001 = (hx0 ^ m01) & TMASK;
        const unsigned i010 = (hx0 ^ m10) & TMASK;
        const unsigned i011 = (hx0 ^ m11) & TMASK;

        float2 f000, f001, f010, f011, f100, f101, f110, f111;

        // x-prime is 1: if x0 even and x1==x0+1, the two x-corners are
        // ADJACENT table entries {2j,2j+1} -> one aligned float4 covers both.
        const bool pairOK = ((x0 & 1) == 0) && (x1 == x0 + 1);
        if (pairOK) {
            const float4* __restrict__ tbl4 = (const float4*)tbl;
            const float4 q00 = tbl4[i000 >> 1];
            const float4 q01 = tbl4[i001 >> 1];
            const float4 q10 = tbl4[i010 >> 1];
            const float4 q11 = tbl4[i011 >> 1];
            f000 = (i000 & 1) ? make_float2(q00.z, q00.w) : make_float2(q00.x, q00.y);
            f100 = (i000 & 1) ? make_float2(q00.x, q00.y) : make_float2(q00.z, q00.w);
            f001 = (i001 & 1) ? make_float2(q01.z, q01.w) : make_float2(q01.x, q01.y);
            f101 = (i001 & 1) ? make_float2(q01.x, q01.y) : make_float2(q01.z, q01.w);
            f010 = (i010 & 1) ? make_float2(q10.z, q10.w) : make_float2(q10.x, q10.y);
            f110 = (i010 & 1) ? make_float2(q10.x, q10.y) : make_float2(q10.z, q10.w);
            f011 = (i011 & 1) ? make_float2(q11.z, q11.w) : make_float2(q11.x, q11.y);
            f111 = (i011 & 1) ? make_float2(q11.x, q11.y) : make_float2(q11.z, q11.w);
        } else {
            const unsigned i100 = (hx1 ^ m00) & TMASK;
            const unsigned i101 = (hx1 ^ m01) & TMASK;
            const unsigned i110 = (hx1 ^ m10) & TMASK;
            const unsigned i111 = (hx1 ^ m11) & TMASK;
            f000 = tbl[i000]; f001 = tbl[i001];
            f010 = tbl[i010]; f011 = tbl[i011];
            f100 = tbl[i100]; f101 = tbl[i101];
            f110 = tbl[i110]; f111 = tbl[i111];
        }

        const float wx0 = 1.f - wx, wy0 = 1.f - wy, wz0 = 1.f - wz;

        const float w000 = wx0 * wy0 * wz0;
        const float w001 = wx0 * wy0 * wz;
        const float w010 = wx0 * wy  * wz0;
        const float w011 = wx0 * wy  * wz;
        const float w100 = wx  * wy0 * wz0;
        const float w101 = wx  * wy0 * wz;
        const float w110 = wx  * wy  * wz0;
        const float w111 = wx  * wy  * wz;

        float a0 = 0.f, a1 = 0.f;
        a0 = fmaf(w000, f000.x, a0); a1 = fmaf(w000, f000.y, a1);
        a0 = fmaf(w001, f001.x, a0); a1 = fmaf(w001, f001.y, a1);
        a0 = fmaf(w010, f010.x, a0); a1 = fmaf(w010, f010.y, a1);
        a0 = fmaf(w011, f011.x, a0); a1 = fmaf(w011, f011.y, a1);
        a0 = fmaf(w100, f100.x, a0); a1 = fmaf(w100, f100.y, a1);
        a0 = fmaf(w101, f101.x, a0); a1 = fmaf(w101, f101.y, a1);
        a0 = fmaf(w110, f110.x, a0); a1 = fmaf(w110, f110.y, a1);
        a0 = fmaf(w111, f111.x, a0); a1 = fmaf(w111, f111.y, a1);

        acc[2 * kk + 0] = a0;
        acc[2 * kk + 1] = a1;
    }

    if (direct) {
        ((float2*)out4)[(size_t)n * 16 + levels[0]] = make_float2(acc[0], acc[1]);
        ((float2*)out4)[(size_t)n * 16 + levels[1]] = make_float2(acc[2], acc[3]);
    } else {
        // stream v: {level v: (x,y), level 15-v: (z,w)}; coalesced NT store
        const float4 o = make_float4(acc[0], acc[1], acc[2], acc[3]);
        const size_t stride = (size_t)nc * 256;
        __builtin_nontemporal_store(*(const f32x4*)&o,
                                    (f32x4*)&ws2[(size_t)v * stride + i]);
    }
}

// ---------------- un-permute: sorted rows -> out rows ----------------
// stream v carries levels (v, 15-v); reassemble the 32-float row in registers.

__global__ __launch_bounds__(256) void k_final(const float4* __restrict__ sorted,
                                               const float4* __restrict__ ws2,
                                               float4* __restrict__ out4,
                                               int N, int nc) {
    const int i = blockIdx.x * 256 + threadIdx.x;
    if (i >= N) return;
    const unsigned wbits = __float_as_uint(sorted[i].w);
    const int n = (int)(wbits & 0xFFFFFFu);
    const size_t stride = (size_t)nc * 256;

    float4 q[8];
    #pragma unroll
    for (int j = 0; j < 8; ++j) {
        f32x4 v = __builtin_nontemporal_load((const f32x4*)&ws2[(size_t)j * stride + i]);
        q[j] = *(const float4*)&v;
    }
    // float2 slot l: l<8 -> (q[l].x, q[l].y); l>=8 -> (q[15-l].z, q[15-l].w)
    #pragma unroll
    for (int kk = 0; kk < 8; ++kk) {
        float4 o;
        if (kk < 4) {
            o = make_float4(q[2 * kk].x, q[2 * kk].y, q[2 * kk + 1].x, q[2 * kk + 1].y);
        } else {
            o = make_float4(q[15 - 2 * kk].z, q[15 - 2 * kk].w,
                            q[14 - 2 * kk].z, q[14 - 2 * kk].w);
        }
        out4[(size_t)n * 8 + kk] = o;
    }
}

// ---------------- fallback (fused one-pass) ----------------

__global__ __launch_bounds__(256) void lotd_fwd_fused(
    const float* __restrict__ xs, const float* __restrict__ params,
    const int* __restrict__ inds, float* __restrict__ out, int N)
{
    const int g = blockIdx.x * 256 + threadIdx.x;
    const int n = g >> 4;
    if (n >= N) return;
    const int l = g & 15;
    const float rm1 = RM1_TAB[l];
    const int rmax = (int)rm1;
    const float x = xs[3 * n], y = xs[3 * n + 1], z = xs[3 * n + 2];
    const int tree = inds[n];
    const float px = (x * 0.5f + 0.5f) * rm1;
    const float py = (y * 0.5f + 0.5f) * rm1;
    const float pz = (z * 0.5f + 0.5f) * rm1;
    const float fx = floorf(px), fy = floorf(py), fz = floorf(pz);
    const float wx = px - fx, wy = py - fy, wz = pz - fz;
    const int ix = (int)fx, iy = (int)fy, iz = (int)fz;
    const int x0 = min(max(ix, 0), rmax), x1 = min(max(ix + 1, 0), rmax);
    const int y0 = min(max(iy, 0), rmax), y1 = min(max(iy + 1, 0), rmax);
    const int z0 = min(max(iz, 0), rmax), z1 = min(max(iz + 1, 0), rmax);
    const unsigned hx0 = (unsigned)x0, hx1 = (unsigned)x1;
    const unsigned hy0 = (unsigned)y0 * 2654435761u, hy1 = (unsigned)y1 * 2654435761u;
    const unsigned hz0 = (unsigned)z0 * 805459861u,  hz1 = (unsigned)z1 * 805459861u;
    const float2* tbl = (const float2*)(params + (size_t)(tree * NLEVELS + l) * (TSIZE * 2));
    const float2 f000 = tbl[(hx0 ^ hy0 ^ hz0) & TMASK];
    const float2 f001 = tbl[(hx0 ^ hy0 ^ hz1) & TMASK];
    const float2 f010 = tbl[(hx0 ^ hy1 ^ hz0) & TMASK];
    const float2 f011 = tbl[(hx0 ^ hy1 ^ hz1) & TMASK];
    const float2 f100 = tbl[(hx1 ^ hy0 ^ hz0) & TMASK];
    const float2 f101 = tbl[(hx1 ^ hy0 ^ hz1) & TMASK];
    const float2 f110 = tbl[(hx1 ^ hy1 ^ hz0) & TMASK];
    const float2 f111 = tbl[(hx1 ^ hy1 ^ hz1) & TMASK];
    const float wx0 = 1.f - wx, wy0 = 1.f - wy, wz0 = 1.f - wz;
    float a0 = 0.f, a1 = 0.f;
    a0 = fmaf(wx0*wy0*wz0, f000.x, a0); a1 = fmaf(wx0*wy0*wz0, f000.y, a1);
    a0 = fmaf(wx0*wy0*wz , f001.x, a0); a1 = fmaf(wx0*wy0*wz , f001.y, a1);
    a0 = fmaf(wx0*wy *wz0, f010.x, a0); a1 = fmaf(wx0*wy *wz0, f010.y, a1);
    a0 = fmaf(wx0*wy *wz , f011.x, a0); a1 = fmaf(wx0*wy *wz , f011.y, a1);
    a0 = fmaf(wx *wy0*wz0, f100.x, a0); a1 = fmaf(wx *wy0*wz0, f100.y, a1);
    a0 = fmaf(wx *wy0*wz , f101.x, a0); a1 = fmaf(wx *wy0*wz , f101.y, a1);
    a0 = fmaf(wx *wy *wz0, f110.x, a0); a1 = fmaf(wx *wy *wz0, f110.y, a1);
    a0 = fmaf(wx *wy *wz , f111.x, a0); a1 = fmaf(wx *wy *wz , f111.y, a1);
    ((float2*)out)[(size_t)n * 16 + l] = make_float2(a0, a1);
}

extern "C" void kernel_launch(void* const* d_in, const int* in_sizes, int n_in,
                              void* d_out, int out_size, void* d_ws, size_t ws_size,
                              hipStream_t stream) {
    const float* xs     = (const float*)d_in[0];
    const float* params = (const float*)d_in[1];
    const int*   inds   = (const int*)d_in[2];
    float*       out    = (float*)d_out;

    const int N = in_sizes[0] / 3;
    const int nc = (N + 255) / 256;
    const int band_sz = (nc + 7) / 8;

    const size_t hist_bytes   = (size_t)NBUCK * 4;               // 128 KB
    const size_t head_bytes   = 2 * hist_bytes;                  // hist + cursor
    const size_t sorted_bytes = ((size_t)N * 16 + 255) & ~(size_t)255;
    const size_t ws2_bytes    = (size_t)nc * 256 * 8 * 16;
    const size_t need_B = head_bytes + sorted_bytes;
    const size_t need_A = need_B + ws2_bytes;

    if (ws_size < need_B) {
        const int total = N * NLEVELS;
        lotd_fwd_fused<<<(total + 255) / 256, 256, 0, stream>>>(xs, params, inds, out, N);
        return;
    }

    unsigned* hist   = (unsigned*)d_ws;
    unsigned* cursor = (unsigned*)((char*)d_ws + hist_bytes);
    float4*   sorted = (float4*)((char*)d_ws + head_bytes);
    float4*   ws2    = (float4*)((char*)d_ws + head_bytes + sorted_bytes);

    hipMemsetAsync(hist, 0, hist_bytes, stream);
    k_hist<<<nc, 256, 0, stream>>>(xs, inds, N, hist);
    k_scan<<<1, 1024, 0, stream>>>(hist, cursor);
    k_scatter<<<nc, 256, 0, stream>>>(xs, inds, N, cursor, sorted);

    const int direct = (ws_size < need_A) ? 1 : 0;
    k_main<<<nc * 8, 256, 0, stream>>>(sorted, params,
                                       direct ? nullptr : ws2,
                                       (float4*)out, N, nc, band_sz, direct);
    if (!direct)
        k_final<<<nc, 256, 0, stream>>>(sorted, ws2, (float4*)out, N, nc);
}